// Round 2
// baseline (130.322 us; speedup 1.0000x reference)
//
#include <hip/hip_runtime.h>

#define N_DIM 4096

typedef float f4  __attribute__((ext_vector_type(4)));
typedef short s8v __attribute__((ext_vector_type(8)));

// fp32 -> bf16 bits, round-to-nearest-even (inputs uniform [0,1]; no NaN path)
static __device__ __forceinline__ unsigned short f2bf(float f) {
    unsigned int u = __builtin_bit_cast(unsigned int, f);
    u = (u + 0x7fffu + ((u >> 16) & 1u)) >> 16;
    return (unsigned short)u;
}
static __device__ __forceinline__ s8v pack8(f4 a, f4 b) {
    s8v h;
    h[0] = (short)f2bf(a[0]); h[1] = (short)f2bf(a[1]);
    h[2] = (short)f2bf(a[2]); h[3] = (short)f2bf(a[3]);
    h[4] = (short)f2bf(b[0]); h[5] = (short)f2bf(b[1]);
    h[6] = (short)f2bf(b[2]); h[7] = (short)f2bf(b[3]);
    return h;
}

__global__ void zero_out_kernel(float* __restrict__ out) {
    if (threadIdx.x == 0 && blockIdx.x == 0) out[0] = 0.f;
}

// One block per 16-row i-tile of X; full N=4096 reduction in-block (no atomics
// on row_sums, no workspace). K-loop: n-chunks of 128, double-buffered LDS,
// register prefetch of chunk c+1 issued before chunk c's MFMAs -> 1 barrier/chunk.
// LDS packets stored lane-consecutive: ds_write_b128 / ds_read_b128 conflict-free.
__global__ __launch_bounds__(256, 1) void fused_kernel(
    const float* __restrict__ zs, const float* __restrict__ X,
    const float* __restrict__ varp, float* __restrict__ out) {
    // packet idx bits (zs): k_lo=idx&15, q=(idx>>4)&3, s=(idx>>6)&3, w=idx>>8
    //   holds zs[16*w + k_lo, n0 + ((idx>>4)&15)*8 + j], j=0..7
    __shared__ s8v zs_l[2][1024];  // 64 k x 128 n bf16, double-buffered (32 KB)
    __shared__ s8v x_l [2][256];   // 16 i x 128 n bf16, double-buffered (8 KB)

    const int tid  = threadIdx.x;
    const int lane = tid & 63;
    const int w    = tid >> 6;     // wave w owns k-slice [16w, 16w+16)
    const int i0   = blockIdx.x * 16;

    f4 acc = {0.f, 0.f, 0.f, 0.f};
    f4 rz[8], rx[2];

    // prefetch + stage chunk 0
    #pragma unroll
    for (int it = 0; it < 4; ++it) {
        int idx = it * 256 + tid;
        const f4* g = (const f4*)(zs + ((idx >> 8) * 16 + (idx & 15)) * N_DIM
                                     + ((idx >> 4) & 15) * 8);
        rz[2 * it] = g[0]; rz[2 * it + 1] = g[1];
    }
    {
        const f4* gx = (const f4*)(X + (size_t)(i0 + (tid & 15)) * N_DIM
                                      + ((tid >> 4) & 15) * 8);
        rx[0] = gx[0]; rx[1] = gx[1];
    }
    #pragma unroll
    for (int it = 0; it < 4; ++it)
        zs_l[0][it * 256 + tid] = pack8(rz[2 * it], rz[2 * it + 1]);
    x_l[0][tid] = pack8(rx[0], rx[1]);

    for (int c = 0; c < 32; ++c) {
        const int cur = c & 1, nxt = cur ^ 1;
        if (c < 31) {  // issue loads for chunk c+1 (in flight across MFMAs)
            const int n0 = (c + 1) * 128;
            #pragma unroll
            for (int it = 0; it < 4; ++it) {
                int idx = it * 256 + tid;
                const f4* g = (const f4*)(zs + ((idx >> 8) * 16 + (idx & 15)) * N_DIM
                                             + n0 + ((idx >> 4) & 15) * 8);
                rz[2 * it] = g[0]; rz[2 * it + 1] = g[1];
            }
            const f4* gx = (const f4*)(X + (size_t)(i0 + (tid & 15)) * N_DIM
                                          + n0 + ((tid >> 4) & 15) * 8);
            rx[0] = gx[0]; rx[1] = gx[1];
        }
        __syncthreads();  // buf[cur] writes from prev iter now visible
        #pragma unroll
        for (int s = 0; s < 4; ++s) {
            s8v a = zs_l[cur][(w * 4 + s) * 64 + lane];
            s8v b = x_l[cur][s * 64 + lane];
            acc = __builtin_amdgcn_mfma_f32_16x16x32_bf16(a, b, acc, 0, 0, 0);
        }
        if (c < 31) {  // convert + write into the OTHER buffer (no 2nd barrier)
            #pragma unroll
            for (int it = 0; it < 4; ++it)
                zs_l[nxt][it * 256 + tid] = pack8(rz[2 * it], rz[2 * it + 1]);
            x_l[nxt][tid] = pack8(rx[0], rx[1]);
        }
    }

    // Epilogue in-block. C/D layout (m89): col = lane&15 (i), row = (lane>>4)*4 + r (k)
    const int   i_g  = i0 + (lane & 15);
    const float diag = X[(size_t)i_g * N_DIM + i_g];
    const float var  = varp[0];
    float lsum = 0.f;
    #pragma unroll
    for (int r = 0; r < 4; ++r) {
        int   k   = 16 * w + ((lane >> 4) << 2) + r;
        float num = zs[k * N_DIM + i_g] * diag;   // exact fp32
        float den = acc[r] - num;
        lsum += num / (var + den);
    }
    #pragma unroll
    for (int off = 32; off >= 1; off >>= 1) lsum += __shfl_down(lsum, off);
    __shared__ float wsum[4];
    if (lane == 0) wsum[w] = lsum;
    __syncthreads();
    if (tid == 0)
        atomicAdd(out, -(wsum[0] + wsum[1] + wsum[2] + wsum[3]) * (1.0f / 64.0f));
}

extern "C" void kernel_launch(void* const* d_in, const int* in_sizes, int n_in,
                              void* d_out, int out_size, void* d_ws, size_t ws_size,
                              hipStream_t stream) {
    const float* zs   = (const float*)d_in[0];
    const float* X    = (const float*)d_in[1];
    const float* varp = (const float*)d_in[2];
    float* out = (float*)d_out;

    hipLaunchKernelGGL(zero_out_kernel, dim3(1), dim3(64), 0, stream, out);
    hipLaunchKernelGGL(fused_kernel, dim3(256), dim3(256), 0, stream, zs, X, varp, out);
}